// Round 1
// baseline (10419.038 us; speedup 1.0000x reference)
//
#include <hip/hip_runtime.h>
#include <math.h>

constexpr int N_TYPES = 4;
constexpr int N_REL   = 8;
constexpr int N_HEADS = 8;
constexpr int IN_DIM  = 256;
constexpr int N_HID   = 128;
constexpr int D_K     = 16;
constexpr int N_LAYERS= 2;
constexpr int NN      = 100000;
constexpr int NE      = 400000;

__device__ __forceinline__ float gelu_f(float x) {
    const float c = 0.7978845608028654f; // sqrt(2/pi)
    float x3 = x * x * x;
    return 0.5f * x * (1.0f + tanhf(c * (x + 0.044715f * x3)));
}
__device__ __forceinline__ float sigmoid_f(float x) {
    return 1.0f / (1.0f + expf(-x));
}
__device__ __forceinline__ unsigned fkey(float f) {
    unsigned b = __float_as_uint(f);
    return b ^ ((b & 0x80000000u) ? 0xFFFFFFFFu : 0x80000000u);
}
__device__ __forceinline__ float fkey_inv(unsigned k) {
    unsigned b = (k & 0x80000000u) ? (k ^ 0x80000000u) : ~k;
    return __uint_as_float(b);
}

// ---------------- bucketing ----------------
__global__ __launch_bounds__(256) void count_kernel(
    const int* __restrict__ ntype, const int* __restrict__ etype,
    unsigned* ncnt, unsigned* ecnt)
{
    int i = blockIdx.x * 256 + threadIdx.x;
    if (i < NN) atomicAdd(&ncnt[ntype[i]], 1u);
    if (i < NE) atomicAdd(&ecnt[etype[i]], 1u);
}

__global__ void offsets_kernel(unsigned* c)
{
    // layout: ncnt[0:4] ncur[4:8] noff[8:13] ecnt[16:24] ecur[24:32] (noff has 5)
    unsigned a = 0;
    for (int t = 0; t < N_TYPES; t++) { c[8 + t] = a; c[4 + t] = a; a += c[t]; }
    c[8 + N_TYPES] = a;
    unsigned b = 0;
    for (int r = 0; r < N_REL; r++) { c[24 + r] = b; b += c[16 + r]; }
}

__global__ __launch_bounds__(256) void scatter_kernel(
    const int* __restrict__ ntype,
    const int* __restrict__ src, const int* __restrict__ tgt,
    const int* __restrict__ etype,
    unsigned* ncur, unsigned* ecur,
    int* __restrict__ nidx,
    int* __restrict__ src_s, int* __restrict__ tgt_s, int* __restrict__ rel_s)
{
    int i = blockIdx.x * 256 + threadIdx.x;
    if (i < NN) {
        int t = ntype[i];
        unsigned p = atomicAdd(&ncur[t], 1u);
        nidx[p] = i;
    }
    if (i < NE) {
        int r = etype[i];
        unsigned p = atomicAdd(&ecur[r], 1u);
        src_s[p] = src[i];
        tgt_s[p] = tgt[i];
        rel_s[p] = r;
    }
}

// ---------------- per-type linear (tiled) ----------------
// MIN: 0 = plain input, 1 = gelu(input)
// MOUT: 0 = tanh(out), 1 = plain (+bias), 2 = skip-mix with hprev
template<int DIN, int MIN, int MOUT>
__global__ __launch_bounds__(256) void ptl_kernel(
    const float* __restrict__ x,
    const int* __restrict__ nidx,
    const unsigned* __restrict__ noff,
    const float* __restrict__ W,     // [4, DIN, 128]
    const float* __restrict__ Bb,    // [4, 128]
    const float* __restrict__ skipv, // [4] or null
    const float* __restrict__ hprev, // [N,128] or null
    float* __restrict__ out)
{
    constexpr int BK = 32;
    const int t = blockIdx.y;
    const unsigned s0 = noff[t], s1 = noff[t + 1];
    const unsigned base = s0 + blockIdx.x * 64u;
    if (base >= s1) return;
    const int nrows = (int)min(64u, s1 - base);

    __shared__ __align__(16) float xs[BK][64];
    __shared__ __align__(16) float wsl[BK][128];
    __shared__ int nid[64];

    const int tid = threadIdx.x;
    if (tid < 64) nid[tid] = nidx[base + (unsigned)min(tid, nrows - 1)];
    __syncthreads();

    const int jg = tid & 31;   // output cols jg*4 .. +4
    const int mg = tid >> 5;   // rows mg*8 .. +8
    float acc[8][4];
    #pragma unroll
    for (int m = 0; m < 8; m++)
        #pragma unroll
        for (int j = 0; j < 4; j++) acc[m][j] = 0.0f;

    const float* Wt = W + (size_t)t * DIN * 128;

    for (int k0 = 0; k0 < DIN; k0 += BK) {
        {
            int row = tid & 63, kg = tid >> 6;
            const float* xp = x + (size_t)nid[row] * DIN + k0 + kg * 8;
            float4 a = *(const float4*)(xp);
            float4 b = *(const float4*)(xp + 4);
            float v[8] = {a.x, a.y, a.z, a.w, b.x, b.y, b.z, b.w};
            #pragma unroll
            for (int i = 0; i < 8; i++) {
                float q = v[i];
                if (MIN == 1) q = gelu_f(q);
                xs[kg * 8 + i][row] = q;
            }
        }
        {
            const float* wp = Wt + (size_t)k0 * 128;
            #pragma unroll
            for (int i = 0; i < 4; i++) {
                int f = tid * 4 + i * 1024;
                *(float4*)&wsl[0][f] = *(const float4*)(wp + f);
            }
        }
        __syncthreads();
        #pragma unroll
        for (int kk = 0; kk < BK; kk++) {
            float4 wv = *(float4*)&wsl[kk][jg * 4];
            float4 xa = *(float4*)&xs[kk][mg * 8];
            float4 xb = *(float4*)&xs[kk][mg * 8 + 4];
            float xv[8] = {xa.x, xa.y, xa.z, xa.w, xb.x, xb.y, xb.z, xb.w};
            #pragma unroll
            for (int m = 0; m < 8; m++) {
                acc[m][0] += xv[m] * wv.x;
                acc[m][1] += xv[m] * wv.y;
                acc[m][2] += xv[m] * wv.z;
                acc[m][3] += xv[m] * wv.w;
            }
        }
        __syncthreads();
    }

    float alpha = 0.0f;
    if (MOUT == 2) alpha = sigmoid_f(skipv[t]);
    float b0 = Bb[t * 128 + jg * 4 + 0];
    float b1 = Bb[t * 128 + jg * 4 + 1];
    float b2 = Bb[t * 128 + jg * 4 + 2];
    float b3 = Bb[t * 128 + jg * 4 + 3];
    #pragma unroll
    for (int m = 0; m < 8; m++) {
        int row = mg * 8 + m;
        if (row < nrows) {
            int n = nid[row];
            float vv[4] = {acc[m][0] + b0, acc[m][1] + b1, acc[m][2] + b2, acc[m][3] + b3};
            float4 o;
            if (MOUT == 0) {
                o.x = tanhf(vv[0]); o.y = tanhf(vv[1]); o.z = tanhf(vv[2]); o.w = tanhf(vv[3]);
            } else if (MOUT == 1) {
                o.x = vv[0]; o.y = vv[1]; o.z = vv[2]; o.w = vv[3];
            } else {
                const float* hp = hprev + (size_t)n * 128 + jg * 4;
                float4 h4 = *(const float4*)hp;
                o.x = vv[0] * alpha + h4.x * (1.0f - alpha);
                o.y = vv[1] * alpha + h4.y * (1.0f - alpha);
                o.z = vv[2] * alpha + h4.z * (1.0f - alpha);
                o.w = vv[3] * alpha + h4.w * (1.0f - alpha);
            }
            *(float4*)&out[(size_t)n * 128 + jg * 4] = o;
        }
    }
}

// ---------------- edge passes ----------------
__global__ __launch_bounds__(256) void e1_score(
    const int* __restrict__ src_s, const int* __restrict__ tgt_s,
    const int* __restrict__ rel_s,
    const float* __restrict__ kbuf, const float* __restrict__ qbuf,
    const float* __restrict__ att,  // [8,8,16,16] (layer slice)
    const float* __restrict__ pri,  // [8,8]
    float* __restrict__ score, unsigned* __restrict__ mkey)
{
    int gid = blockIdx.x * 256 + threadIdx.x;
    int pos = gid >> 3, h = gid & 7;
    if (pos >= NE) return;
    int src = src_s[pos], tgt = tgt_s[pos], r = rel_s[pos];
    const float* kp = kbuf + (size_t)src * 128 + h * 16;
    const float* qp = qbuf + (size_t)tgt * 128 + h * 16;
    const float* A = att + ((r * 8 + h) << 8);

    float kv[16], qv[16];
    #pragma unroll
    for (int i = 0; i < 4; i++) {
        float4 a = ((const float4*)kp)[i];
        kv[4*i] = a.x; kv[4*i+1] = a.y; kv[4*i+2] = a.z; kv[4*i+3] = a.w;
        float4 b = ((const float4*)qp)[i];
        qv[4*i] = b.x; qv[4*i+1] = b.y; qv[4*i+2] = b.z; qv[4*i+3] = b.w;
    }
    float acc[16];
    #pragma unroll
    for (int f = 0; f < 16; f++) acc[f] = 0.0f;
    #pragma unroll
    for (int d = 0; d < 16; d++) {
        float kd = kv[d];
        const float4* Ar = (const float4*)(A + d * 16);
        #pragma unroll
        for (int fg = 0; fg < 4; fg++) {
            float4 a = Ar[fg];
            acc[4*fg+0] += kd * a.x; acc[4*fg+1] += kd * a.y;
            acc[4*fg+2] += kd * a.z; acc[4*fg+3] += kd * a.w;
        }
    }
    float s = 0.0f;
    #pragma unroll
    for (int f = 0; f < 16; f++) s += acc[f] * qv[f];
    s *= pri[r * 8 + h] * 0.25f;
    score[(size_t)pos * 8 + h] = s;
    atomicMax(&mkey[(size_t)tgt * 8 + h], fkey(s));
}

__global__ __launch_bounds__(256) void e2_norm(
    const int* __restrict__ tgt_s,
    float* __restrict__ score,
    const unsigned* __restrict__ mkey,
    float* __restrict__ z)
{
    int gid = blockIdx.x * 256 + threadIdx.x;
    int pos = gid >> 3, h = gid & 7;
    if (pos >= NE) return;
    int tgt = tgt_s[pos];
    float m = fkey_inv(mkey[(size_t)tgt * 8 + h]);
    float ev = expf(score[(size_t)pos * 8 + h] - m);
    score[(size_t)pos * 8 + h] = ev;
    atomicAdd(&z[(size_t)tgt * 8 + h], ev);
}

__global__ __launch_bounds__(256) void e3_agg(
    const int* __restrict__ src_s, const int* __restrict__ tgt_s,
    const int* __restrict__ rel_s,
    const float* __restrict__ vbuf,
    const float* __restrict__ msg,  // [8,8,16,16]
    const float* __restrict__ score,
    const float* __restrict__ z,
    float* __restrict__ agg)
{
    int gid = blockIdx.x * 256 + threadIdx.x;
    int pos = gid >> 3, h = gid & 7;
    if (pos >= NE) return;
    int src = src_s[pos], tgt = tgt_s[pos], r = rel_s[pos];
    const float* vp = vbuf + (size_t)src * 128 + h * 16;
    const float* M = msg + ((r * 8 + h) << 8);

    float vv[16];
    #pragma unroll
    for (int i = 0; i < 4; i++) {
        float4 a = ((const float4*)vp)[i];
        vv[4*i] = a.x; vv[4*i+1] = a.y; vv[4*i+2] = a.z; vv[4*i+3] = a.w;
    }
    float acc[16];
    #pragma unroll
    for (int f = 0; f < 16; f++) acc[f] = 0.0f;
    #pragma unroll
    for (int d = 0; d < 16; d++) {
        float vd = vv[d];
        const float4* Mr = (const float4*)(M + d * 16);
        #pragma unroll
        for (int fg = 0; fg < 4; fg++) {
            float4 a = Mr[fg];
            acc[4*fg+0] += vd * a.x; acc[4*fg+1] += vd * a.y;
            acc[4*fg+2] += vd * a.z; acc[4*fg+3] += vd * a.w;
        }
    }
    float at = score[(size_t)pos * 8 + h] / (z[(size_t)tgt * 8 + h] + 1e-9f);
    float* ap = agg + (size_t)tgt * 128 + h * 16;
    #pragma unroll
    for (int f = 0; f < 16; f++) atomicAdd(&ap[f], at * acc[f]);
}

// ---------------- launch ----------------
extern "C" void kernel_launch(void* const* d_in, const int* in_sizes, int n_in,
                              void* d_out, int out_size, void* d_ws, size_t ws_size,
                              hipStream_t stream)
{
    const float* node_feature = (const float*)d_in[0];
    const int*   node_type    = (const int*)d_in[1];
    const int*   edge_index   = (const int*)d_in[2];
    const int*   edge_type    = (const int*)d_in[3];
    const float* adapt_w      = (const float*)d_in[4];
    const float* adapt_b      = (const float*)d_in[5];
    const float* k_w = (const float*)d_in[6];
    const float* k_b = (const float*)d_in[7];
    const float* q_w = (const float*)d_in[8];
    const float* q_b = (const float*)d_in[9];
    const float* v_w = (const float*)d_in[10];
    const float* v_b = (const float*)d_in[11];
    const float* a_w = (const float*)d_in[12];
    const float* a_b = (const float*)d_in[13];
    const float* rel_pri = (const float*)d_in[14];
    const float* rel_att = (const float*)d_in[15];
    const float* rel_msg = (const float*)d_in[16];
    const float* skip    = (const float*)d_in[17];

    const int* src = edge_index;
    const int* tgt = edge_index + NE;

    float* OUT = (float*)d_out;

    char* w = (char*)d_ws;
    auto alloc = [&](size_t bytes) -> void* {
        void* p = (void*)w;
        w += (bytes + 255) & ~(size_t)255;
        return p;
    };
    float*    B0    = (float*)alloc((size_t)NN * 128 * 4);
    float*    B1    = (float*)alloc((size_t)NN * 128 * 4);
    float*    B2    = (float*)alloc((size_t)NN * 128 * 4);
    float*    score = (float*)alloc((size_t)NE * 8 * 4);
    unsigned* mkey  = (unsigned*)alloc((size_t)NN * 8 * 4);
    float*    zbuf  = (float*)alloc((size_t)NN * 8 * 4);
    int*      nidx  = (int*)alloc((size_t)NN * 4);
    int*      src_s = (int*)alloc((size_t)NE * 4);
    int*      tgt_s = (int*)alloc((size_t)NE * 4);
    int*      rel_s = (int*)alloc((size_t)NE * 4);
    unsigned* cnts  = (unsigned*)alloc(64 * 4);

    unsigned* ncnt = cnts;          // 4
    unsigned* ncur = cnts + 4;      // 4
    unsigned* noff = cnts + 8;      // 5
    unsigned* ecnt = cnts + 16;     // 8
    unsigned* ecur = cnts + 24;     // 8

    hipMemsetAsync(cnts, 0, 64 * 4, stream);
    {
        int blocks = (NE + 255) / 256;
        count_kernel<<<blocks, 256, 0, stream>>>(node_type, edge_type, ncnt, ecnt);
        offsets_kernel<<<1, 1, 0, stream>>>(cnts);
        scatter_kernel<<<blocks, 256, 0, stream>>>(node_type, src, tgt, edge_type,
                                                   ncur, ecur, nidx, src_s, tgt_s, rel_s);
    }

    dim3 pgrid((NN + 63) / 64, N_TYPES);
    ptl_kernel<IN_DIM, 0, 0><<<pgrid, 256, 0, stream>>>(
        node_feature, nidx, noff, adapt_w, adapt_b, nullptr, nullptr, B0);

    const int eblocks = (NE * 8 + 255) / 256;

    for (int l = 0; l < N_LAYERS; l++) {
        float* hin  = l ? B2 : B0;
        float* kb_  = l ? B0 : B1;
        float* qb_  = l ? B1 : B2;
        float* vb_  = OUT;
        float* aggb = kb_;
        float* hout = l ? OUT : B2;

        const float* kwl = k_w + (size_t)l * N_TYPES * 128 * 128;
        const float* kbl = k_b + (size_t)l * N_TYPES * 128;
        const float* qwl = q_w + (size_t)l * N_TYPES * 128 * 128;
        const float* qbl = q_b + (size_t)l * N_TYPES * 128;
        const float* vwl = v_w + (size_t)l * N_TYPES * 128 * 128;
        const float* vbl = v_b + (size_t)l * N_TYPES * 128;
        const float* awl = a_w + (size_t)l * N_TYPES * 128 * 128;
        const float* abl = a_b + (size_t)l * N_TYPES * 128;
        const float* pril = rel_pri + (size_t)l * N_REL * N_HEADS;
        const float* attl = rel_att + (size_t)l * N_REL * N_HEADS * D_K * D_K;
        const float* msgl = rel_msg + (size_t)l * N_REL * N_HEADS * D_K * D_K;
        const float* skipl = skip + (size_t)l * N_TYPES;

        ptl_kernel<N_HID, 0, 1><<<pgrid, 256, 0, stream>>>(
            hin, nidx, noff, kwl, kbl, nullptr, nullptr, kb_);
        ptl_kernel<N_HID, 0, 1><<<pgrid, 256, 0, stream>>>(
            hin, nidx, noff, qwl, qbl, nullptr, nullptr, qb_);
        ptl_kernel<N_HID, 0, 1><<<pgrid, 256, 0, stream>>>(
            hin, nidx, noff, vwl, vbl, nullptr, nullptr, vb_);

        hipMemsetAsync(mkey, 0, (size_t)NN * 8 * 4, stream);
        e1_score<<<eblocks, 256, 0, stream>>>(src_s, tgt_s, rel_s, kb_, qb_,
                                              attl, pril, score, mkey);
        hipMemsetAsync(zbuf, 0, (size_t)NN * 8 * 4, stream);
        e2_norm<<<eblocks, 256, 0, stream>>>(tgt_s, score, mkey, zbuf);
        hipMemsetAsync(aggb, 0, (size_t)NN * 128 * 4, stream);
        e3_agg<<<eblocks, 256, 0, stream>>>(src_s, tgt_s, rel_s, vb_, msgl,
                                            score, zbuf, aggb);

        ptl_kernel<N_HID, 1, 2><<<pgrid, 256, 0, stream>>>(
            aggb, nidx, noff, awl, abl, skipl, hin, hout);
    }
}

// Round 2
// 2225.600 us; speedup vs baseline: 4.6815x; 4.6815x over previous
//
#include <hip/hip_runtime.h>
#include <math.h>

constexpr int N_TYPES = 4;
constexpr int N_REL   = 8;
constexpr int N_HEADS = 8;
constexpr int IN_DIM  = 256;
constexpr int N_HID   = 128;
constexpr int D_K     = 16;
constexpr int N_LAYERS= 2;
constexpr int NN      = 100000;
constexpr int NE      = 400000;
constexpr int NBLK    = (NN + 255) / 256;   // scan blocks

__device__ __forceinline__ float gelu_f(float x) {
    const float c = 0.7978845608028654f; // sqrt(2/pi)
    float x3 = x * x * x;
    return 0.5f * x * (1.0f + tanhf(c * (x + 0.044715f * x3)));
}
__device__ __forceinline__ float sigmoid_f(float x) {
    return 1.0f / (1.0f + expf(-x));
}

// ---------------- bucketing: nodes by type, edges by target ----------------
__global__ __launch_bounds__(256) void count2_kernel(
    const int* __restrict__ ntype, const int* __restrict__ tgt,
    unsigned* ncnt, unsigned* tcnt)
{
    int i = blockIdx.x * 256 + threadIdx.x;
    if (i < NN) atomicAdd(&ncnt[ntype[i]], 1u);
    if (i < NE) atomicAdd(&tcnt[tgt[i]], 1u);
}

__global__ void node_offsets_kernel(unsigned* c)
{
    // layout: ncnt[0:4] ncur[4:8] noff[8:13]
    unsigned a = 0;
    for (int t = 0; t < N_TYPES; t++) { c[8 + t] = a; c[4 + t] = a; a += c[t]; }
    c[8 + N_TYPES] = a;
}

// hierarchical exclusive scan over tcnt[NN] -> eoff[NN+1]
__global__ __launch_bounds__(256) void scan1_kernel(
    const unsigned* __restrict__ cnt, unsigned* __restrict__ eoff,
    unsigned* __restrict__ bsum)
{
    __shared__ unsigned sh[256];
    int i = blockIdx.x * 256 + threadIdx.x;
    unsigned v = (i < NN) ? cnt[i] : 0u;
    sh[threadIdx.x] = v;
    __syncthreads();
    for (int off = 1; off < 256; off <<= 1) {
        unsigned add = (threadIdx.x >= off) ? sh[threadIdx.x - off] : 0u;
        __syncthreads();
        sh[threadIdx.x] += add;
        __syncthreads();
    }
    if (i < NN) eoff[i] = sh[threadIdx.x] - v;      // block-local exclusive
    if (threadIdx.x == 255) bsum[blockIdx.x] = sh[255];
}

__global__ __launch_bounds__(512) void scan2_kernel(unsigned* __restrict__ bsum)
{
    __shared__ unsigned sh[512];
    int i = threadIdx.x;
    unsigned v = (i < NBLK) ? bsum[i] : 0u;
    sh[i] = v;
    __syncthreads();
    for (int off = 1; off < 512; off <<= 1) {
        unsigned add = (i >= off) ? sh[i - off] : 0u;
        __syncthreads();
        sh[i] += add;
        __syncthreads();
    }
    if (i < NBLK) bsum[i] = sh[i] - v;              // exclusive block offsets
}

__global__ __launch_bounds__(256) void scan3_kernel(
    unsigned* __restrict__ eoff, const unsigned* __restrict__ bsum,
    unsigned* __restrict__ ecur)
{
    int i = blockIdx.x * 256 + threadIdx.x;
    if (i < NN) {
        unsigned v = eoff[i] + bsum[blockIdx.x];
        eoff[i] = v;
        ecur[i] = v;
    }
    if (i == 0) eoff[NN] = (unsigned)NE;
}

__global__ __launch_bounds__(256) void scatter2_kernel(
    const int* __restrict__ ntype,
    const int* __restrict__ src, const int* __restrict__ tgt,
    const int* __restrict__ etype,
    unsigned* ncur, unsigned* ecur,
    int* __restrict__ nidx,
    int* __restrict__ src_t, int* __restrict__ rel_t)
{
    int i = blockIdx.x * 256 + threadIdx.x;
    if (i < NN) {
        int t = ntype[i];
        unsigned p = atomicAdd(&ncur[t], 1u);
        nidx[p] = i;
    }
    if (i < NE) {
        int t = tgt[i];
        unsigned p = atomicAdd(&ecur[t], 1u);
        src_t[p] = src[i];
        rel_t[p] = etype[i];
    }
}

// ---------------- per-type linear (tiled) ----------------
// MIN: 0 = plain input, 1 = gelu(input)
// MOUT: 0 = tanh(out), 1 = plain (+bias), 2 = skip-mix with hprev
template<int DIN, int MIN, int MOUT>
__global__ __launch_bounds__(256) void ptl_kernel(
    const float* __restrict__ x,
    const int* __restrict__ nidx,
    const unsigned* __restrict__ noff,
    const float* __restrict__ W,     // [4, DIN, 128]
    const float* __restrict__ Bb,    // [4, 128]
    const float* __restrict__ skipv, // [4] or null
    const float* __restrict__ hprev, // [N,128] or null
    float* __restrict__ out)
{
    constexpr int BK = 32;
    const int t = blockIdx.y;
    const unsigned s0 = noff[t], s1 = noff[t + 1];
    const unsigned base = s0 + blockIdx.x * 64u;
    if (base >= s1) return;
    const int nrows = (int)min(64u, s1 - base);

    __shared__ __align__(16) float xs[BK][64];
    __shared__ __align__(16) float wsl[BK][128];
    __shared__ int nid[64];

    const int tid = threadIdx.x;
    if (tid < 64) nid[tid] = nidx[base + (unsigned)min(tid, nrows - 1)];
    __syncthreads();

    const int jg = tid & 31;   // output cols jg*4 .. +4
    const int mg = tid >> 5;   // rows mg*8 .. +8
    float acc[8][4];
    #pragma unroll
    for (int m = 0; m < 8; m++)
        #pragma unroll
        for (int j = 0; j < 4; j++) acc[m][j] = 0.0f;

    const float* Wt = W + (size_t)t * DIN * 128;

    for (int k0 = 0; k0 < DIN; k0 += BK) {
        {
            int row = tid & 63, kg = tid >> 6;
            const float* xp = x + (size_t)nid[row] * DIN + k0 + kg * 8;
            float4 a = *(const float4*)(xp);
            float4 b = *(const float4*)(xp + 4);
            float v[8] = {a.x, a.y, a.z, a.w, b.x, b.y, b.z, b.w};
            #pragma unroll
            for (int i = 0; i < 8; i++) {
                float q = v[i];
                if (MIN == 1) q = gelu_f(q);
                xs[kg * 8 + i][row] = q;
            }
        }
        {
            const float* wp = Wt + (size_t)k0 * 128;
            #pragma unroll
            for (int i = 0; i < 4; i++) {
                int f = tid * 4 + i * 1024;
                *(float4*)&wsl[0][f] = *(const float4*)(wp + f);
            }
        }
        __syncthreads();
        #pragma unroll
        for (int kk = 0; kk < BK; kk++) {
            float4 wv = *(float4*)&wsl[kk][jg * 4];
            float4 xa = *(float4*)&xs[kk][mg * 8];
            float4 xb = *(float4*)&xs[kk][mg * 8 + 4];
            float xv[8] = {xa.x, xa.y, xa.z, xa.w, xb.x, xb.y, xb.z, xb.w};
            #pragma unroll
            for (int m = 0; m < 8; m++) {
                acc[m][0] += xv[m] * wv.x;
                acc[m][1] += xv[m] * wv.y;
                acc[m][2] += xv[m] * wv.z;
                acc[m][3] += xv[m] * wv.w;
            }
        }
        __syncthreads();
    }

    float alpha = 0.0f;
    if (MOUT == 2) alpha = sigmoid_f(skipv[t]);
    float b0 = Bb[t * 128 + jg * 4 + 0];
    float b1 = Bb[t * 128 + jg * 4 + 1];
    float b2 = Bb[t * 128 + jg * 4 + 2];
    float b3 = Bb[t * 128 + jg * 4 + 3];
    #pragma unroll
    for (int m = 0; m < 8; m++) {
        int row = mg * 8 + m;
        if (row < nrows) {
            int n = nid[row];
            float vv[4] = {acc[m][0] + b0, acc[m][1] + b1, acc[m][2] + b2, acc[m][3] + b3};
            float4 o;
            if (MOUT == 0) {
                o.x = tanhf(vv[0]); o.y = tanhf(vv[1]); o.z = tanhf(vv[2]); o.w = tanhf(vv[3]);
            } else if (MOUT == 1) {
                o.x = vv[0]; o.y = vv[1]; o.z = vv[2]; o.w = vv[3];
            } else {
                const float* hp = hprev + (size_t)n * 128 + jg * 4;
                float4 h4 = *(const float4*)hp;
                o.x = vv[0] * alpha + h4.x * (1.0f - alpha);
                o.y = vv[1] * alpha + h4.y * (1.0f - alpha);
                o.z = vv[2] * alpha + h4.z * (1.0f - alpha);
                o.w = vv[3] * alpha + h4.w * (1.0f - alpha);
            }
            *(float4*)&out[(size_t)n * 128 + jg * 4] = o;
        }
    }
}

// ---------------- fused edge phase: score + softmax + aggregate ----------------
// One target per 128 threads (2 waves); lane li = h*16 + j, heads 0-3 in the
// first wave of the pair, 4-7 in the second -> all shuffles stay in-wave.
// score_e  = k_src^T (A_r q_tgt) * pri * 0.25   (aq precomputed per present rel)
// agg      = [ sum_r (sum_{e in r} p_e * v_e) * M_r ] / (z + 1e-9)
// No global atomics; no __syncthreads (all LDS sharing is intra-wave).
__global__ __launch_bounds__(256) void hgt_edge_fused(
    const int* __restrict__ src_t,
    const int* __restrict__ rel_t,
    const unsigned* __restrict__ eoff,  // [NN+1]
    const float* __restrict__ kbuf,
    const float* __restrict__ vbuf,
    const float* __restrict__ att,      // [8,8,16,16] layer slice
    const float* __restrict__ msg,      // [8,8,16,16]
    const float* __restrict__ pri,      // [8,8]
    float* __restrict__ qagg)           // q in, agg out (in-place per target)
{
    __shared__ float aq_lds[2][1024];
    __shared__ float s_lds[2][1024];
    const int tid  = threadIdx.x;
    const int tsel = tid >> 7;          // which target in the block
    const int li   = tid & 127;         // (h, j)
    const int h    = li >> 4;
    const int j    = li & 15;
    const int hb   = tid & 0x30;        // head-base lane within wave
    const int t    = blockIdx.x * 2 + tsel;
    if (t >= NN) return;

    float* sl = s_lds[tsel];
    float* al = aq_lds[tsel];

    const unsigned e0 = eoff[t];
    const unsigned e1 = eoff[t + 1];

    #pragma unroll
    for (int r = 0; r < 8; r++) sl[r * 128 + li] = 0.0f;

    const float qo = qagg[(size_t)t * 128 + li];

    // which relations occur in this segment (uniform across the 128 threads)
    unsigned mask = 0;
    for (unsigned e = e0; e < e1; e++) mask |= (1u << rel_t[e]);

    // aq[r][h][j] = sum_f A[r][h][j][f] * q[h][f], scaled by pri*0.25
    for (int r = 0; r < 8; r++) {
        if (!((mask >> r) & 1)) continue;
        const float* Ar = att + (((r * 8 + h) * 16 + j) * 16);
        float ar[16];
        ((float4*)ar)[0] = ((const float4*)Ar)[0];
        ((float4*)ar)[1] = ((const float4*)Ar)[1];
        ((float4*)ar)[2] = ((const float4*)Ar)[2];
        ((float4*)ar)[3] = ((const float4*)Ar)[3];
        float acc = 0.0f;
        #pragma unroll
        for (int f = 0; f < 16; f++)
            acc += ar[f] * __shfl(qo, hb + f, 64);
        al[r * 128 + li] = acc * pri[r * 8 + h] * 0.25f;
    }

    // online softmax over the segment, accumulating per-relation p*v in LDS
    float m = -INFINITY, z = 0.0f;
    float* slp = sl + li;
    const float* alp = al + li;
    for (unsigned e = e0; e < e1; e++) {
        const int sidx = src_t[e];
        const int r = rel_t[e];
        const float kv = kbuf[(size_t)sidx * 128 + li];
        const float vv = vbuf[(size_t)sidx * 128 + li];
        float sp = kv * alp[r * 128];
        sp += __shfl_xor(sp, 1);
        sp += __shfl_xor(sp, 2);
        sp += __shfl_xor(sp, 4);
        sp += __shfl_xor(sp, 8);
        const float mn = fmaxf(m, sp);
        const float scale = __expf(m - mn);   // 0 on first edge (m = -inf)
        const float p = __expf(sp - mn);
        z = z * scale + p;
        if (scale != 1.0f) {
            #pragma unroll
            for (int r2 = 0; r2 < 8; r2++) slp[r2 * 128] *= scale;
        }
        m = mn;
        slp[r * 128] += p * vv;
    }

    // apply message matrices once per present relation, normalize, write agg
    float acc = 0.0f;
    for (int r = 0; r < 8; r++) {
        if (!((mask >> r) & 1)) continue;
        const float* Mr = msg + ((r * 8 + h) * 256) + j;
        const float* sb = sl + r * 128 + h * 16;
        #pragma unroll
        for (int d = 0; d < 16; d++)
            acc += sb[d] * Mr[d * 16];   // sb[d]: LDS broadcast; Mr: coalesced
    }
    qagg[(size_t)t * 128 + li] = acc / (z + 1e-9f);
}

// ---------------- launch ----------------
extern "C" void kernel_launch(void* const* d_in, const int* in_sizes, int n_in,
                              void* d_out, int out_size, void* d_ws, size_t ws_size,
                              hipStream_t stream)
{
    const float* node_feature = (const float*)d_in[0];
    const int*   node_type    = (const int*)d_in[1];
    const int*   edge_index   = (const int*)d_in[2];
    const int*   edge_type    = (const int*)d_in[3];
    const float* adapt_w      = (const float*)d_in[4];
    const float* adapt_b      = (const float*)d_in[5];
    const float* k_w = (const float*)d_in[6];
    const float* k_b = (const float*)d_in[7];
    const float* q_w = (const float*)d_in[8];
    const float* q_b = (const float*)d_in[9];
    const float* v_w = (const float*)d_in[10];
    const float* v_b = (const float*)d_in[11];
    const float* a_w = (const float*)d_in[12];
    const float* a_b = (const float*)d_in[13];
    const float* rel_pri = (const float*)d_in[14];
    const float* rel_att = (const float*)d_in[15];
    const float* rel_msg = (const float*)d_in[16];
    const float* skip    = (const float*)d_in[17];

    const int* src = edge_index;
    const int* tgt = edge_index + NE;

    float* OUT = (float*)d_out;

    char* w = (char*)d_ws;
    auto alloc = [&](size_t bytes) -> void* {
        void* p = (void*)w;
        w += (bytes + 255) & ~(size_t)255;
        return p;
    };
    float*    B0    = (float*)alloc((size_t)NN * 128 * 4);
    float*    B1    = (float*)alloc((size_t)NN * 128 * 4);
    float*    B2    = (float*)alloc((size_t)NN * 128 * 4);
    int*      nidx  = (int*)alloc((size_t)NN * 4);
    int*      src_t = (int*)alloc((size_t)NE * 4);
    int*      rel_t = (int*)alloc((size_t)NE * 4);
    unsigned* tcnt  = (unsigned*)alloc((size_t)NN * 4);
    unsigned* eoff  = (unsigned*)alloc((size_t)(NN + 1) * 4);
    unsigned* ecur  = (unsigned*)alloc((size_t)NN * 4);
    unsigned* bsum  = (unsigned*)alloc((size_t)NBLK * 4);
    unsigned* cnts  = (unsigned*)alloc(16 * 4);

    unsigned* ncnt = cnts;          // 4
    unsigned* ncur = cnts + 4;      // 4
    unsigned* noff = cnts + 8;      // 5

    hipMemsetAsync(cnts, 0, 16 * 4, stream);
    hipMemsetAsync(tcnt, 0, (size_t)NN * 4, stream);

    const int gblocks = (NE + 255) / 256;
    count2_kernel<<<gblocks, 256, 0, stream>>>(node_type, tgt, ncnt, tcnt);
    node_offsets_kernel<<<1, 1, 0, stream>>>(cnts);
    scan1_kernel<<<NBLK, 256, 0, stream>>>(tcnt, eoff, bsum);
    scan2_kernel<<<1, 512, 0, stream>>>(bsum);
    scan3_kernel<<<NBLK, 256, 0, stream>>>(eoff, bsum, ecur);
    scatter2_kernel<<<gblocks, 256, 0, stream>>>(node_type, src, tgt, edge_type,
                                                 ncur, ecur, nidx, src_t, rel_t);

    dim3 pgrid((NN + 63) / 64, N_TYPES);
    ptl_kernel<IN_DIM, 0, 0><<<pgrid, 256, 0, stream>>>(
        node_feature, nidx, noff, adapt_w, adapt_b, nullptr, nullptr, B0);

    const int fblocks = (NN + 1) / 2;

    for (int l = 0; l < N_LAYERS; l++) {
        float* hin  = l ? B1 : B0;
        float* kb_  = l ? B0 : B1;
        float* qb_  = B2;           // q, then agg in-place
        float* vb_  = OUT;
        float* hout = l ? OUT : B1;

        const float* kwl = k_w + (size_t)l * N_TYPES * 128 * 128;
        const float* kbl = k_b + (size_t)l * N_TYPES * 128;
        const float* qwl = q_w + (size_t)l * N_TYPES * 128 * 128;
        const float* qbl = q_b + (size_t)l * N_TYPES * 128;
        const float* vwl = v_w + (size_t)l * N_TYPES * 128 * 128;
        const float* vbl = v_b + (size_t)l * N_TYPES * 128;
        const float* awl = a_w + (size_t)l * N_TYPES * 128 * 128;
        const float* abl = a_b + (size_t)l * N_TYPES * 128;
        const float* pril = rel_pri + (size_t)l * N_REL * N_HEADS;
        const float* attl = rel_att + (size_t)l * N_REL * N_HEADS * D_K * D_K;
        const float* msgl = rel_msg + (size_t)l * N_REL * N_HEADS * D_K * D_K;
        const float* skipl = skip + (size_t)l * N_TYPES;

        ptl_kernel<N_HID, 0, 1><<<pgrid, 256, 0, stream>>>(
            hin, nidx, noff, kwl, kbl, nullptr, nullptr, kb_);
        ptl_kernel<N_HID, 0, 1><<<pgrid, 256, 0, stream>>>(
            hin, nidx, noff, qwl, qbl, nullptr, nullptr, qb_);
        ptl_kernel<N_HID, 0, 1><<<pgrid, 256, 0, stream>>>(
            hin, nidx, noff, vwl, vbl, nullptr, nullptr, vb_);

        hgt_edge_fused<<<fblocks, 256, 0, stream>>>(
            src_t, rel_t, eoff, kb_, vb_, attl, msgl, pril, qb_);

        ptl_kernel<N_HID, 1, 2><<<pgrid, 256, 0, stream>>>(
            qb_, nidx, noff, awl, abl, skipl, hin, hout);
    }
}

// Round 3
// 1287.350 us; speedup vs baseline: 8.0934x; 1.7288x over previous
//
#include <hip/hip_runtime.h>
#include <math.h>

constexpr int N_TYPES = 4;
constexpr int N_REL   = 8;
constexpr int N_HEADS = 8;
constexpr int IN_DIM  = 256;
constexpr int N_HID   = 128;
constexpr int D_K     = 16;
constexpr int N_LAYERS= 2;
constexpr int NN      = 100000;
constexpr int NE      = 400000;
constexpr int NBLK    = (NN + 255) / 256;   // scan blocks

__device__ __forceinline__ float gelu_f(float x) {
    const float c = 0.7978845608028654f; // sqrt(2/pi)
    float x3 = x * x * x;
    return 0.5f * x * (1.0f + tanhf(c * (x + 0.044715f * x3)));
}
__device__ __forceinline__ float sigmoid_f(float x) {
    return 1.0f / (1.0f + expf(-x));
}

// ---------------- bucketing: nodes by type, edges by target ----------------
// Node-type counters are only 4 addresses -> wave-aggregate the atomics.
__global__ __launch_bounds__(256) void count2_kernel(
    const int* __restrict__ ntype, const int* __restrict__ tgt,
    unsigned* ncnt, unsigned* tcnt)
{
    int i = blockIdx.x * 256 + threadIdx.x;
    int lane = threadIdx.x & 63;
    int t = (i < NN) ? ntype[i] : -1;
    #pragma unroll
    for (int tt = 0; tt < N_TYPES; tt++) {
        unsigned long long m = __ballot(t == tt);
        if (m != 0ull && lane == __ffsll((unsigned long long)m) - 1)
            atomicAdd(&ncnt[tt], (unsigned)__popcll(m));
    }
    if (i < NE) atomicAdd(&tcnt[tgt[i]], 1u);
}

__global__ void node_offsets_kernel(unsigned* c)
{
    // layout: ncnt[0:4] ncur[4:8] noff[8:13]
    unsigned a = 0;
    for (int t = 0; t < N_TYPES; t++) { c[8 + t] = a; c[4 + t] = a; a += c[t]; }
    c[8 + N_TYPES] = a;
}

// hierarchical exclusive scan over tcnt[NN] -> eoff[NN+1]
__global__ __launch_bounds__(256) void scan1_kernel(
    const unsigned* __restrict__ cnt, unsigned* __restrict__ eoff,
    unsigned* __restrict__ bsum)
{
    __shared__ unsigned sh[256];
    int i = blockIdx.x * 256 + threadIdx.x;
    unsigned v = (i < NN) ? cnt[i] : 0u;
    sh[threadIdx.x] = v;
    __syncthreads();
    for (int off = 1; off < 256; off <<= 1) {
        unsigned add = (threadIdx.x >= off) ? sh[threadIdx.x - off] : 0u;
        __syncthreads();
        sh[threadIdx.x] += add;
        __syncthreads();
    }
    if (i < NN) eoff[i] = sh[threadIdx.x] - v;      // block-local exclusive
    if (threadIdx.x == 255) bsum[blockIdx.x] = sh[255];
}

__global__ __launch_bounds__(512) void scan2_kernel(unsigned* __restrict__ bsum)
{
    __shared__ unsigned sh[512];
    int i = threadIdx.x;
    unsigned v = (i < NBLK) ? bsum[i] : 0u;
    sh[i] = v;
    __syncthreads();
    for (int off = 1; off < 512; off <<= 1) {
        unsigned add = (i >= off) ? sh[i - off] : 0u;
        __syncthreads();
        sh[i] += add;
        __syncthreads();
    }
    if (i < NBLK) bsum[i] = sh[i] - v;              // exclusive block offsets
}

__global__ __launch_bounds__(256) void scan3_kernel(
    unsigned* __restrict__ eoff, const unsigned* __restrict__ bsum,
    unsigned* __restrict__ ecur)
{
    int i = blockIdx.x * 256 + threadIdx.x;
    if (i < NN) {
        unsigned v = eoff[i] + bsum[blockIdx.x];
        eoff[i] = v;
        ecur[i] = v;
    }
    if (i == 0) eoff[NN] = (unsigned)NE;
}

__global__ __launch_bounds__(256) void scatter2_kernel(
    const int* __restrict__ ntype,
    const int* __restrict__ src, const int* __restrict__ tgt,
    const int* __restrict__ etype,
    unsigned* ncur, unsigned* ecur,
    int* __restrict__ nidx,
    int* __restrict__ src_t, int* __restrict__ rel_t)
{
    int i = blockIdx.x * 256 + threadIdx.x;
    int lane = threadIdx.x & 63;
    int t = (i < NN) ? ntype[i] : -1;
    // wave-aggregated slot assignment: 1 atomic per (wave, type) not per node
    #pragma unroll
    for (int tt = 0; tt < N_TYPES; tt++) {
        unsigned long long m = __ballot(t == tt);
        if (m == 0ull) continue;
        int leader = __ffsll((unsigned long long)m) - 1;
        unsigned base = 0;
        if (lane == leader) base = atomicAdd(&ncur[tt], (unsigned)__popcll(m));
        base = __shfl(base, leader, 64);
        if (t == tt) {
            unsigned rank = (unsigned)__popcll(m & ((1ull << lane) - 1ull));
            nidx[base + rank] = i;
        }
    }
    if (i < NE) {
        int tg = tgt[i];
        unsigned p = atomicAdd(&ecur[tg], 1u);   // 100K distinct addrs, low contention
        src_t[p] = src[i];
        rel_t[p] = etype[i];
    }
}

// ---------------- per-type linear (tiled) ----------------
// MIN: 0 = plain input, 1 = gelu(input)
// MOUT: 0 = tanh(out), 1 = plain (+bias), 2 = skip-mix with hprev
template<int DIN, int MIN, int MOUT>
__global__ __launch_bounds__(256) void ptl_kernel(
    const float* __restrict__ x,
    const int* __restrict__ nidx,
    const unsigned* __restrict__ noff,
    const float* __restrict__ W,     // [4, DIN, 128]
    const float* __restrict__ Bb,    // [4, 128]
    const float* __restrict__ skipv, // [4] or null
    const float* __restrict__ hprev, // [N,128] or null
    float* __restrict__ out)
{
    constexpr int BK = 32;
    const int t = blockIdx.y;
    const unsigned s0 = noff[t], s1 = noff[t + 1];
    const unsigned base = s0 + blockIdx.x * 64u;
    if (base >= s1) return;
    const int nrows = (int)min(64u, s1 - base);

    __shared__ __align__(16) float xs[BK][64];
    __shared__ __align__(16) float wsl[BK][128];
    __shared__ int nid[64];

    const int tid = threadIdx.x;
    if (tid < 64) nid[tid] = nidx[base + (unsigned)min(tid, nrows - 1)];
    __syncthreads();

    const int jg = tid & 31;   // output cols jg*4 .. +4
    const int mg = tid >> 5;   // rows mg*8 .. +8
    float acc[8][4];
    #pragma unroll
    for (int m = 0; m < 8; m++)
        #pragma unroll
        for (int j = 0; j < 4; j++) acc[m][j] = 0.0f;

    const float* Wt = W + (size_t)t * DIN * 128;

    for (int k0 = 0; k0 < DIN; k0 += BK) {
        {
            int row = tid & 63, kg = tid >> 6;
            const float* xp = x + (size_t)nid[row] * DIN + k0 + kg * 8;
            float4 a = *(const float4*)(xp);
            float4 b = *(const float4*)(xp + 4);
            float v[8] = {a.x, a.y, a.z, a.w, b.x, b.y, b.z, b.w};
            #pragma unroll
            for (int i = 0; i < 8; i++) {
                float q = v[i];
                if (MIN == 1) q = gelu_f(q);
                xs[kg * 8 + i][row] = q;
            }
        }
        {
            const float* wp = Wt + (size_t)k0 * 128;
            #pragma unroll
            for (int i = 0; i < 4; i++) {
                int f = tid * 4 + i * 1024;
                *(float4*)&wsl[0][f] = *(const float4*)(wp + f);
            }
        }
        __syncthreads();
        #pragma unroll
        for (int kk = 0; kk < BK; kk++) {
            float4 wv = *(float4*)&wsl[kk][jg * 4];
            float4 xa = *(float4*)&xs[kk][mg * 8];
            float4 xb = *(float4*)&xs[kk][mg * 8 + 4];
            float xv[8] = {xa.x, xa.y, xa.z, xa.w, xb.x, xb.y, xb.z, xb.w};
            #pragma unroll
            for (int m = 0; m < 8; m++) {
                acc[m][0] += xv[m] * wv.x;
                acc[m][1] += xv[m] * wv.y;
                acc[m][2] += xv[m] * wv.z;
                acc[m][3] += xv[m] * wv.w;
            }
        }
        __syncthreads();
    }

    float alpha = 0.0f;
    if (MOUT == 2) alpha = sigmoid_f(skipv[t]);
    float b0 = Bb[t * 128 + jg * 4 + 0];
    float b1 = Bb[t * 128 + jg * 4 + 1];
    float b2 = Bb[t * 128 + jg * 4 + 2];
    float b3 = Bb[t * 128 + jg * 4 + 3];
    #pragma unroll
    for (int m = 0; m < 8; m++) {
        int row = mg * 8 + m;
        if (row < nrows) {
            int n = nid[row];
            float vv[4] = {acc[m][0] + b0, acc[m][1] + b1, acc[m][2] + b2, acc[m][3] + b3};
            float4 o;
            if (MOUT == 0) {
                o.x = tanhf(vv[0]); o.y = tanhf(vv[1]); o.z = tanhf(vv[2]); o.w = tanhf(vv[3]);
            } else if (MOUT == 1) {
                o.x = vv[0]; o.y = vv[1]; o.z = vv[2]; o.w = vv[3];
            } else {
                const float* hp = hprev + (size_t)n * 128 + jg * 4;
                float4 h4 = *(const float4*)hp;
                o.x = vv[0] * alpha + h4.x * (1.0f - alpha);
                o.y = vv[1] * alpha + h4.y * (1.0f - alpha);
                o.z = vv[2] * alpha + h4.z * (1.0f - alpha);
                o.w = vv[3] * alpha + h4.w * (1.0f - alpha);
            }
            *(float4*)&out[(size_t)n * 128 + jg * 4] = o;
        }
    }
}

// ---------------- fused edge phase: score + softmax + aggregate ----------------
// One target per 128 threads (2 waves); lane li = h*16 + j, heads 0-3 in the
// first wave of the pair, 4-7 in the second -> all shuffles stay in-wave.
__global__ __launch_bounds__(256) void hgt_edge_fused(
    const int* __restrict__ src_t,
    const int* __restrict__ rel_t,
    const unsigned* __restrict__ eoff,  // [NN+1]
    const float* __restrict__ kbuf,
    const float* __restrict__ vbuf,
    const float* __restrict__ att,      // [8,8,16,16] layer slice
    const float* __restrict__ msg,      // [8,8,16,16]
    const float* __restrict__ pri,      // [8,8]
    float* __restrict__ qagg)           // q in, agg out (in-place per target)
{
    __shared__ float aq_lds[2][1024];
    __shared__ float s_lds[2][1024];
    const int tid  = threadIdx.x;
    const int tsel = tid >> 7;          // which target in the block
    const int li   = tid & 127;         // (h, j)
    const int h    = li >> 4;
    const int j    = li & 15;
    const int hb   = tid & 0x30;        // head-base lane within wave
    const int t    = blockIdx.x * 2 + tsel;
    if (t >= NN) return;

    float* sl = s_lds[tsel];
    float* al = aq_lds[tsel];

    const unsigned e0 = eoff[t];
    const unsigned e1 = eoff[t + 1];

    #pragma unroll
    for (int r = 0; r < 8; r++) sl[r * 128 + li] = 0.0f;

    const float qo = qagg[(size_t)t * 128 + li];

    // which relations occur in this segment (uniform across the 128 threads)
    unsigned mask = 0;
    for (unsigned e = e0; e < e1; e++) mask |= (1u << rel_t[e]);

    // aq[r][h][j] = sum_f A[r][h][j][f] * q[h][f], scaled by pri*0.25
    for (int r = 0; r < 8; r++) {
        if (!((mask >> r) & 1)) continue;
        const float* Ar = att + (((r * 8 + h) * 16 + j) * 16);
        float ar[16];
        ((float4*)ar)[0] = ((const float4*)Ar)[0];
        ((float4*)ar)[1] = ((const float4*)Ar)[1];
        ((float4*)ar)[2] = ((const float4*)Ar)[2];
        ((float4*)ar)[3] = ((const float4*)Ar)[3];
        float acc = 0.0f;
        #pragma unroll
        for (int f = 0; f < 16; f++)
            acc += ar[f] * __shfl(qo, hb + f, 64);
        al[r * 128 + li] = acc * pri[r * 8 + h] * 0.25f;
    }

    // online softmax over the segment, accumulating per-relation p*v in LDS
    float m = -INFINITY, z = 0.0f;
    float* slp = sl + li;
    const float* alp = al + li;
    for (unsigned e = e0; e < e1; e++) {
        const int sidx = src_t[e];
        const int r = rel_t[e];
        const float kv = kbuf[(size_t)sidx * 128 + li];
        const float vv = vbuf[(size_t)sidx * 128 + li];
        float sp = kv * alp[r * 128];
        sp += __shfl_xor(sp, 1);
        sp += __shfl_xor(sp, 2);
        sp += __shfl_xor(sp, 4);
        sp += __shfl_xor(sp, 8);
        const float mn = fmaxf(m, sp);
        const float scale = __expf(m - mn);   // 0 on first edge (m = -inf)
        const float p = __expf(sp - mn);
        z = z * scale + p;
        if (scale != 1.0f) {
            #pragma unroll
            for (int r2 = 0; r2 < 8; r2++) slp[r2 * 128] *= scale;
        }
        m = mn;
        slp[r * 128] += p * vv;
    }

    // apply message matrices once per present relation, normalize, write agg
    float acc = 0.0f;
    for (int r = 0; r < 8; r++) {
        if (!((mask >> r) & 1)) continue;
        const float* Mr = msg + ((r * 8 + h) * 256) + j;
        const float* sb = sl + r * 128 + h * 16;
        #pragma unroll
        for (int d = 0; d < 16; d++)
            acc += sb[d] * Mr[d * 16];   // sb[d]: LDS broadcast; Mr: coalesced
    }
    qagg[(size_t)t * 128 + li] = acc / (z + 1e-9f);
}

// ---------------- launch ----------------
extern "C" void kernel_launch(void* const* d_in, const int* in_sizes, int n_in,
                              void* d_out, int out_size, void* d_ws, size_t ws_size,
                              hipStream_t stream)
{
    const float* node_feature = (const float*)d_in[0];
    const int*   node_type    = (const int*)d_in[1];
    const int*   edge_index   = (const int*)d_in[2];
    const int*   edge_type    = (const int*)d_in[3];
    const float* adapt_w      = (const float*)d_in[4];
    const float* adapt_b      = (const float*)d_in[5];
    const float* k_w = (const float*)d_in[6];
    const float* k_b = (const float*)d_in[7];
    const float* q_w = (const float*)d_in[8];
    const float* q_b = (const float*)d_in[9];
    const float* v_w = (const float*)d_in[10];
    const float* v_b = (const float*)d_in[11];
    const float* a_w = (const float*)d_in[12];
    const float* a_b = (const float*)d_in[13];
    const float* rel_pri = (const float*)d_in[14];
    const float* rel_att = (const float*)d_in[15];
    const float* rel_msg = (const float*)d_in[16];
    const float* skip    = (const float*)d_in[17];

    const int* src = edge_index;
    const int* tgt = edge_index + NE;

    float* OUT = (float*)d_out;

    char* w = (char*)d_ws;
    auto alloc = [&](size_t bytes) -> void* {
        void* p = (void*)w;
        w += (bytes + 255) & ~(size_t)255;
        return p;
    };
    float*    B0    = (float*)alloc((size_t)NN * 128 * 4);
    float*    B1    = (float*)alloc((size_t)NN * 128 * 4);
    float*    B2    = (float*)alloc((size_t)NN * 128 * 4);
    int*      nidx  = (int*)alloc((size_t)NN * 4);
    int*      src_t = (int*)alloc((size_t)NE * 4);
    int*      rel_t = (int*)alloc((size_t)NE * 4);
    unsigned* tcnt  = (unsigned*)alloc((size_t)NN * 4);
    unsigned* eoff  = (unsigned*)alloc((size_t)(NN + 1) * 4);
    unsigned* ecur  = (unsigned*)alloc((size_t)NN * 4);
    unsigned* bsum  = (unsigned*)alloc((size_t)NBLK * 4);
    unsigned* cnts  = (unsigned*)alloc(16 * 4);

    unsigned* ncnt = cnts;          // 4
    unsigned* ncur = cnts + 4;      // 4
    unsigned* noff = cnts + 8;      // 5

    hipMemsetAsync(cnts, 0, 16 * 4, stream);
    hipMemsetAsync(tcnt, 0, (size_t)NN * 4, stream);

    const int gblocks = (NE + 255) / 256;
    count2_kernel<<<gblocks, 256, 0, stream>>>(node_type, tgt, ncnt, tcnt);
    node_offsets_kernel<<<1, 1, 0, stream>>>(cnts);
    scan1_kernel<<<NBLK, 256, 0, stream>>>(tcnt, eoff, bsum);
    scan2_kernel<<<1, 512, 0, stream>>>(bsum);
    scan3_kernel<<<NBLK, 256, 0, stream>>>(eoff, bsum, ecur);
    scatter2_kernel<<<gblocks, 256, 0, stream>>>(node_type, src, tgt, edge_type,
                                                 ncur, ecur, nidx, src_t, rel_t);

    dim3 pgrid((NN + 63) / 64, N_TYPES);
    ptl_kernel<IN_DIM, 0, 0><<<pgrid, 256, 0, stream>>>(
        node_feature, nidx, noff, adapt_w, adapt_b, nullptr, nullptr, B0);

    const int fblocks = (NN + 1) / 2;

    for (int l = 0; l < N_LAYERS; l++) {
        float* hin  = l ? B1 : B0;
        float* kb_  = l ? B0 : B1;
        float* qb_  = B2;           // q, then agg in-place
        float* vb_  = OUT;
        float* hout = l ? OUT : B1;

        const float* kwl = k_w + (size_t)l * N_TYPES * 128 * 128;
        const float* kbl = k_b + (size_t)l * N_TYPES * 128;
        const float* qwl = q_w + (size_t)l * N_TYPES * 128 * 128;
        const float* qbl = q_b + (size_t)l * N_TYPES * 128;
        const float* vwl = v_w + (size_t)l * N_TYPES * 128 * 128;
        const float* vbl = v_b + (size_t)l * N_TYPES * 128;
        const float* awl = a_w + (size_t)l * N_TYPES * 128 * 128;
        const float* abl = a_b + (size_t)l * N_TYPES * 128;
        const float* pril = rel_pri + (size_t)l * N_REL * N_HEADS;
        const float* attl = rel_att + (size_t)l * N_REL * N_HEADS * D_K * D_K;
        const float* msgl = rel_msg + (size_t)l * N_REL * N_HEADS * D_K * D_K;
        const float* skipl = skip + (size_t)l * N_TYPES;

        ptl_kernel<N_HID, 0, 1><<<pgrid, 256, 0, stream>>>(
            hin, nidx, noff, kwl, kbl, nullptr, nullptr, kb_);
        ptl_kernel<N_HID, 0, 1><<<pgrid, 256, 0, stream>>>(
            hin, nidx, noff, qwl, qbl, nullptr, nullptr, qb_);
        ptl_kernel<N_HID, 0, 1><<<pgrid, 256, 0, stream>>>(
            hin, nidx, noff, vwl, vbl, nullptr, nullptr, vb_);

        hgt_edge_fused<<<fblocks, 256, 0, stream>>>(
            src_t, rel_t, eoff, kb_, vb_, attl, msgl, pril, qb_);

        ptl_kernel<N_HID, 1, 2><<<pgrid, 256, 0, stream>>>(
            qb_, nidx, noff, awl, abl, skipl, hin, hout);
    }
}